// Round 3
// baseline (229.173 us; speedup 1.0000x reference)
//
#include <hip/hip_runtime.h>
#include <math.h>

#define VOCAB 32000
#define D 768
#define S 512
#define W 300
#define B 64
#define LMAX 4

typedef float f32x4 __attribute__((ext_vector_type(4)));

// ---------------------------------------------------------------------------
// Kernel 1: per-batch "first break" scan.
// ---------------------------------------------------------------------------
__global__ __launch_bounds__(64) void find_first_kernel(
    const int* __restrict__ word_index,  // (B, W, 3)
    int* __restrict__ first_out,         // (B)
    int* __restrict__ fill_id_out)       // (B)
{
    const int b = blockIdx.x;
    const int lane = threadIdx.x;  // 0..63
    int my_first = W;
    for (int w = lane; w < W; w += 64) {
        const int base = (b * W + w) * 3;
        const int st = word_index[base + 1];
        const int en = word_index[base + 2];
        if (en < S && (en - st) <= 0) my_first = min(my_first, w);
    }
    #pragma unroll
    for (int off = 32; off > 0; off >>= 1)
        my_first = min(my_first, __shfl_xor(my_first, off));
    if (lane == 0) {
        first_out[b] = my_first;
        const int fw = min(my_first, W - 1);
        fill_id_out[b] = word_index[(b * W + fw) * 3 + 0];
    }
}

__device__ __forceinline__ float wave_bcast_sum(float p) {
    #pragma unroll
    for (int off = 32; off > 0; off >>= 1) p += __shfl_xor(p, off);
    return p;
}

// ---------------------------------------------------------------------------
// Kernel 2: one wave per (b, w), online-softmax single pass over char rows.
// XCD-aware swizzle: blocks dispatch round-robin over 8 XCDs (blk % 8), so
// map xcd = blk % 8 -> batches [xcd*8, xcd*8+8). All 75 blocks of a batch
// land on ONE XCD -> each ernie row fetched into exactly one L2 (1.5 MB/batch
// fits 4 MB L2), eliminating 8x L2-fill replication over the LLC fabric.
// ---------------------------------------------------------------------------
__global__ __launch_bounds__(256) void pool_kernel(
    const float* __restrict__ ernie,      // (B, S, D)
    const float* __restrict__ emb,        // (VOCAB, D)
    const int*   __restrict__ word_index, // (B, W, 3)
    const int*   __restrict__ first_arr,  // (B)
    const int*   __restrict__ fill_arr,   // (B)
    float* __restrict__ out)              // (B, W, D)
{
    // ---- XCD-aware work remap: grid = 4800 = 8 xcd * 8 batches * 75 blocks
    const int blk  = blockIdx.x;
    const int xcd  = blk & 7;        // round-robin XCD assignment
    const int slot = blk >> 3;       // 0..599 within this XCD
    const int bloc = slot / 75;      // 0..7: which of this XCD's batches
    const int wg   = slot - bloc * 75;
    const int b    = (xcd << 3) + bloc;
    const int w    = wg * 4 + (threadIdx.x >> 6);

    int gwave = b * W + w;
    gwave = __builtin_amdgcn_readfirstlane(gwave);  // force wave-uniform/SGPR
    const int lane = threadIdx.x & 63;

    const int base = gwave * 3;
    const int wid = word_index[base + 0];  // scalar loads (uniform address)
    const int st  = word_index[base + 1];
    const int en  = word_index[base + 2];

    f32x4* __restrict__ outp = (f32x4*)(out + (size_t)gwave * D);

    // ---- fill path: w >= first[b] -> out = emb[fill_id] ----
    if (w >= first_arr[b]) {
        const f32x4* src = (const f32x4*)(emb + (size_t)fill_arr[b] * D);
        #pragma unroll
        for (int k = 0; k < 3; k++)
            __builtin_nontemporal_store(src[lane + 64 * k], &outp[lane + 64 * k]);
        return;
    }

    // ---- word embedding row (both remaining paths need it) ----
    const f32x4* wep = (const f32x4*)(emb + (size_t)wid * D);
    f32x4 we0 = wep[lane], we1 = wep[lane + 64], we2 = wep[lane + 128];

    // ---- out-of-range path: en >= S -> out = we ----
    if (en >= S) {
        __builtin_nontemporal_store(we0, &outp[lane]);
        __builtin_nontemporal_store(we1, &outp[lane + 64]);
        __builtin_nontemporal_store(we2, &outp[lane + 128]);
        return;
    }

    // ---- pooling path: online softmax, single pass over char rows ----
    const int span_eff = min(max(en - st, 1), LMAX);
    const f32x4* erow = (const f32x4*)(ernie + (size_t)b * S * D);  // 192 f32x4/row

    float m = -INFINITY, denom = 0.f;
    f32x4 acc0 = 0.f, acc1 = 0.f, acc2 = 0.f;

    int p0 = min(max(st, 0), S - 1);
    f32x4 c0 = erow[p0 * 192 + lane];
    f32x4 c1 = erow[p0 * 192 + lane + 64];
    f32x4 c2 = erow[p0 * 192 + lane + 128];

    #pragma unroll
    for (int l = 0; l < LMAX; ++l) {
        if (l >= span_eff) break;  // scalar branch (span_eff is SGPR)
        f32x4 n0, n1, n2;
        if (l + 1 < span_eff) {    // depth-1 prefetch of next row
            int pn = min(max(st + l + 1, 0), S - 1);
            n0 = erow[pn * 192 + lane];
            n1 = erow[pn * 192 + lane + 64];
            n2 = erow[pn * 192 + lane + 128];
        } else {
            n0 = c0; n1 = c1; n2 = c2;
        }
        f32x4 pv = c0 * we0 + c1 * we1 + c2 * we2;
        float p = pv.x + pv.y + pv.z + pv.w;
        p = wave_bcast_sum(p);          // all lanes hold full dot
        float mn = fmaxf(m, p);
        float scale = expf(m - mn);     // 1st iter: expf(-inf)=0
        float e = expf(p - mn);
        denom = denom * scale + e;
        acc0 = acc0 * scale + e * c0;
        acc1 = acc1 * scale + e * c1;
        acc2 = acc2 * scale + e * c2;
        m = mn;
        c0 = n0; c1 = n1; c2 = n2;
    }

    const float inv = 1.f / denom;
    __builtin_nontemporal_store(acc0 * inv, &outp[lane]);
    __builtin_nontemporal_store(acc1 * inv, &outp[lane + 64]);
    __builtin_nontemporal_store(acc2 * inv, &outp[lane + 128]);
}

extern "C" void kernel_launch(void* const* d_in, const int* in_sizes, int n_in,
                              void* d_out, int out_size, void* d_ws, size_t ws_size,
                              hipStream_t stream) {
    const float* ernie      = (const float*)d_in[0];  // (B, S, D) fp32
    const float* emb        = (const float*)d_in[1];  // (VOCAB, D) fp32
    const int*   word_index = (const int*)d_in[2];    // (B, W, 3) int32
    float* out = (float*)d_out;                       // (B, W, D) fp32

    int* first_arr = (int*)d_ws;        // B ints
    int* fill_arr  = first_arr + B;     // B ints

    find_first_kernel<<<B, 64, 0, stream>>>(word_index, first_arr, fill_arr);

    const int total_waves = B * W;                 // 19200
    const int grid = total_waves / 4;              // 4800 blocks of 256
    pool_kernel<<<grid, 256, 0, stream>>>(ernie, emb, word_index,
                                          first_arr, fill_arr, out);
}

// Round 4
// 228.936 us; speedup vs baseline: 1.0010x; 1.0010x over previous
//
#include <hip/hip_runtime.h>
#include <math.h>

#define VOCAB 32000
#define D 768
#define S 512
#define W 300
#define B 64
#define LMAX 4
#define GW 4            // words per block (4 waves x 1 word)
#define WGPB 75         // word-groups per batch = W/GW
#define MAXROWS 12      // GW * max span (3)
#define ROWB 3072       // bytes per 768-float row

typedef float f32x4 __attribute__((ext_vector_type(4)));

// ---------------------------------------------------------------------------
// Kernel 1: per-batch "first break" scan (unchanged).
// ---------------------------------------------------------------------------
__global__ __launch_bounds__(64) void find_first_kernel(
    const int* __restrict__ word_index,  // (B, W, 3)
    int* __restrict__ first_out,         // (B)
    int* __restrict__ fill_id_out)       // (B)
{
    const int b = blockIdx.x;
    const int lane = threadIdx.x;  // 0..63
    int my_first = W;
    for (int w = lane; w < W; w += 64) {
        const int base = (b * W + w) * 3;
        const int st = word_index[base + 1];
        const int en = word_index[base + 2];
        if (en < S && (en - st) <= 0) my_first = min(my_first, w);
    }
    #pragma unroll
    for (int off = 32; off > 0; off >>= 1)
        my_first = min(my_first, __shfl_xor(my_first, off));
    if (lane == 0) {
        first_out[b] = my_first;
        const int fw = min(my_first, W - 1);
        fill_id_out[b] = word_index[(b * W + fw) * 3 + 0];
    }
}

__device__ __forceinline__ float wave_bcast_sum(float p) {
    #pragma unroll
    for (int off = 32; off > 0; off >>= 1) p += __shfl_xor(p, off);
    return p;
}

// async global->LDS, 16B per lane. HW computes LDS dst = uniform base + lane*16.
__device__ __forceinline__ void async_copy16(const void* g, void* l) {
    __builtin_amdgcn_global_load_lds(
        (const __attribute__((address_space(1))) void*)g,
        (__attribute__((address_space(3))) void*)l,
        16, 0, 0);
}

// ---------------------------------------------------------------------------
// Kernel 2: one block per 4 consecutive words of one batch.
// Spans partition the sequence (st(w+1)==en(w)), so the block's char rows are
// ONE contiguous range [st(w0), min(en(w3),S)) of <=12 rows (36 KB). Stage it
// async into LDS with back-to-back global_load_lds dwordx4 (no VGPR dep),
// overlapped with the we-row gather; one barrier; compute dots from LDS.
// ---------------------------------------------------------------------------
__global__ __launch_bounds__(256) void pool_kernel(
    const float* __restrict__ ernie,      // (B, S, D)
    const float* __restrict__ emb,        // (VOCAB, D)
    const int*   __restrict__ word_index, // (B, W, 3)
    const int*   __restrict__ first_arr,  // (B)
    const int*   __restrict__ fill_arr,   // (B)
    float* __restrict__ out)              // (B, W, D)
{
    __shared__ __align__(16) char smem[MAXROWS * ROWB];

    const int blk = blockIdx.x;
    const int b   = blk / WGPB;
    const int wg  = blk - b * WGPB;
    const int w0  = wg * GW;
    const int lane   = threadIdx.x & 63;
    const int waveid = __builtin_amdgcn_readfirstlane(threadIdx.x >> 6);
    const int w      = w0 + waveid;
    const int gwave  = b * W + w;

    // ---- block-uniform staging row range (scalar loads) ----
    const int st0 = word_index[(b * W + w0) * 3 + 1];
    const int en3 = word_index[(b * W + w0 + GW - 1) * 3 + 2];
    int row_lo = max(min(st0, S), 0);
    int row_hi = min(en3, S);
    int nrows  = min(max(row_hi - row_lo, 0), MAXROWS);

    // ---- per-wave word data (wave-uniform -> scalar loads) ----
    const int wid = word_index[gwave * 3 + 0];
    const int st  = word_index[gwave * 3 + 1];
    const int en  = word_index[gwave * 3 + 2];
    const int first = first_arr[b];
    const int rowid = (w >= first) ? fill_arr[b] : wid;

    // ---- issue the (we | fill) embedding row gather; stays in flight ----
    const f32x4* wep = (const f32x4*)(emb + (size_t)rowid * D);
    f32x4 we0 = wep[lane], we1 = wep[lane + 64], we2 = wep[lane + 128];

    // ---- async stage ernie rows [row_lo, row_hi) into LDS (1KB chunks) ----
    const char* gbase = (const char*)(ernie + ((size_t)b * S + row_lo) * D);
    const int nchunk = nrows * 3;   // ROWB/1024 = 3 chunks per row
    for (int c = waveid; c < nchunk; c += 4)
        async_copy16(gbase + c * 1024 + lane * 16, smem + c * 1024);

    __syncthreads();   // drains vmcnt (staging + we loads)

    f32x4* __restrict__ outp = (f32x4*)(out + (size_t)gwave * D);

    // ---- fill path (w >= first) or out-of-range copy (en >= S): out = row ----
    if (w >= first || en >= S) {
        __builtin_nontemporal_store(we0, &outp[lane]);
        __builtin_nontemporal_store(we1, &outp[lane + 64]);
        __builtin_nontemporal_store(we2, &outp[lane + 128]);
        return;
    }

    // ---- pooling path: online softmax over LDS-resident char rows ----
    const int span_eff = min(max(en - st, 1), LMAX);
    const char* lbase = smem + (size_t)(st - row_lo) * ROWB;

    float m = -INFINITY, denom = 0.f;
    f32x4 acc0 = 0.f, acc1 = 0.f, acc2 = 0.f;

    #pragma unroll
    for (int l = 0; l < LMAX; ++l) {
        if (l >= span_eff) break;   // scalar branch
        const f32x4* cp = (const f32x4*)(lbase + l * ROWB);
        f32x4 c0 = cp[lane];
        f32x4 c1 = cp[lane + 64];
        f32x4 c2 = cp[lane + 128];
        f32x4 pv = c0 * we0 + c1 * we1 + c2 * we2;
        float p = pv.x + pv.y + pv.z + pv.w;
        p = wave_bcast_sum(p);          // all lanes hold full dot
        float mn = fmaxf(m, p);
        float scale = expf(m - mn);     // 1st iter: expf(-inf)=0
        float e = expf(p - mn);
        denom = denom * scale + e;
        acc0 = acc0 * scale + e * c0;
        acc1 = acc1 * scale + e * c1;
        acc2 = acc2 * scale + e * c2;
        m = mn;
    }

    const float inv = 1.f / denom;
    __builtin_nontemporal_store(acc0 * inv, &outp[lane]);
    __builtin_nontemporal_store(acc1 * inv, &outp[lane + 64]);
    __builtin_nontemporal_store(acc2 * inv, &outp[lane + 128]);
}

extern "C" void kernel_launch(void* const* d_in, const int* in_sizes, int n_in,
                              void* d_out, int out_size, void* d_ws, size_t ws_size,
                              hipStream_t stream) {
    const float* ernie      = (const float*)d_in[0];  // (B, S, D) fp32
    const float* emb        = (const float*)d_in[1];  // (VOCAB, D) fp32
    const int*   word_index = (const int*)d_in[2];    // (B, W, 3) int32
    float* out = (float*)d_out;                       // (B, W, D) fp32

    int* first_arr = (int*)d_ws;        // B ints
    int* fill_arr  = first_arr + B;     // B ints

    find_first_kernel<<<B, 64, 0, stream>>>(word_index, first_arr, fill_arr);

    const int grid = B * WGPB;          // 4800 blocks of 256 threads
    pool_kernel<<<grid, 256, 0, stream>>>(ernie, emb, word_index,
                                          first_arr, fill_arr, out);
}